// Round 1
// baseline (239.026 us; speedup 1.0000x reference)
//
#include <hip/hip_runtime.h>

// NMS3D: x (4,2,64,256,256) f32, 3x3x3 neighborhood-max excluding center,
// edge padding == index clamping (center sneaks into max at boundaries in
// BOTH ref and clamped impl -> boundary shell outputs 0; exact match).

constexpr int D_   = 64;
constexpr int H_   = 256;
constexpr int W_   = 256;
constexpr int HW_  = H_ * W_;
constexpr int NVOL = 8;    // B * CH
constexpr int DC   = 16;   // depth slices emitted per block

__device__ __forceinline__ float f3(float a, float b, float c) {
    return fmaxf(fmaxf(a, b), c);
}

__global__ __launch_bounds__(256, 4)
void nms3d(const float* __restrict__ x, float* __restrict__ out)
{
    const int tx = threadIdx.x;             // 0..63 -> covers W via float4
    const int ty = threadIdx.y;             // 0..3
    const int h  = (blockIdx.y << 2) + ty;  // 0..255
    const int n  = blockIdx.z;              // 0..7
    const int z0 = blockIdx.x * DC;

    const float* __restrict__ base  = x   + (size_t)n * D_ * HW_;
    float* __restrict__       obase = out + (size_t)n * D_ * HW_;

    const int r0 = (h == 0)      ? 0      : h - 1;
    const int r2 = (h == H_ - 1) ? H_ - 1 : h + 1;
    const int c  = tx << 2;

    // rolling depth state
    float4 vm9_pp = make_float4(0.f, 0.f, 0.f, 0.f);  // vmax9[z-2]
    float4 vm9_p  = make_float4(0.f, 0.f, 0.f, 0.f);  // vmax9[z-1]
    float4 cr8_p  = make_float4(0.f, 0.f, 0.f, 0.f);  // cross8[z-1]
    float4 vprev  = make_float4(0.f, 0.f, 0.f, 0.f);  // v[z-1]

    for (int zi = z0 - 1; zi <= z0 + DC; ++zi) {
        const int zc = min(max(zi, 0), D_ - 1);       // depth clamp == edge pad
        const float* sp = base + (size_t)zc * HW_;

        const float4 a = *(const float4*)(sp + r0 * W_ + c);
        const float4 b = *(const float4*)(sp + h  * W_ + c);
        const float4 d = *(const float4*)(sp + r2 * W_ + c);

        // horizontal halo via wave shuffle (wave == one full W row)
        float aL = __shfl_up(a.w, 1);   if (tx == 0)  aL = a.x;
        float bL = __shfl_up(b.w, 1);   if (tx == 0)  bL = b.x;
        float dL = __shfl_up(d.w, 1);   if (tx == 0)  dL = d.x;
        float aR = __shfl_down(a.x, 1); if (tx == 63) aR = a.w;
        float bR = __shfl_down(b.x, 1); if (tx == 63) bR = b.w;
        float dR = __shfl_down(d.x, 1); if (tx == 63) dR = d.w;

        // horizontal 3-max per row
        float4 ha, hb, hd, nb;
        ha.x = f3(aL, a.x, a.y);  ha.y = f3(a.x, a.y, a.z);
        ha.z = f3(a.y, a.z, a.w); ha.w = f3(a.z, a.w, aR);
        hb.x = f3(bL, b.x, b.y);  hb.y = f3(b.x, b.y, b.z);
        hb.z = f3(b.y, b.z, b.w); hb.w = f3(b.z, b.w, bR);
        hd.x = f3(dL, d.x, d.y);  hd.y = f3(d.x, d.y, d.z);
        hd.z = f3(d.y, d.z, d.w); hd.w = f3(d.z, d.w, dR);
        // mid-row horizontal max EXCLUDING center
        nb.x = fmaxf(bL, b.y);  nb.y = fmaxf(b.x, b.z);
        nb.z = fmaxf(b.y, b.w); nb.w = fmaxf(b.z, bR);

        float4 cur, c8;                       // vmax9[zc], cross8[zc]
        cur.x = f3(ha.x, hb.x, hd.x); cur.y = f3(ha.y, hb.y, hd.y);
        cur.z = f3(ha.z, hb.z, hd.z); cur.w = f3(ha.w, hb.w, hd.w);
        c8.x  = f3(ha.x, hd.x, nb.x); c8.y  = f3(ha.y, hd.y, nb.y);
        c8.z  = f3(ha.z, hd.z, nb.z); c8.w  = f3(ha.w, hd.w, nb.w);

        if (zi > z0) {
            // emit out[zi-1]: max_nc = max(vmax9[zi-2], cross8[zi-1], vmax9[zi])
            float4 mx, o;
            mx.x = f3(vm9_pp.x, cr8_p.x, cur.x);
            mx.y = f3(vm9_pp.y, cr8_p.y, cur.y);
            mx.z = f3(vm9_pp.z, cr8_p.z, cur.z);
            mx.w = f3(vm9_pp.w, cr8_p.w, cur.w);
            o.x = vprev.x > mx.x ? vprev.x : 0.0f;
            o.y = vprev.y > mx.y ? vprev.y : 0.0f;
            o.z = vprev.z > mx.z ? vprev.z : 0.0f;
            o.w = vprev.w > mx.w ? vprev.w : 0.0f;
            *(float4*)(obase + (size_t)(zi - 1) * HW_ + (size_t)h * W_ + c) = o;
        }
        vm9_pp = vm9_p; vm9_p = cur; cr8_p = c8; vprev = b;
    }
}

extern "C" void kernel_launch(void* const* d_in, const int* in_sizes, int n_in,
                              void* d_out, int out_size, void* d_ws, size_t ws_size,
                              hipStream_t stream)
{
    const float* x = (const float*)d_in[0];
    float* out = (float*)d_out;
    dim3 block(64, 4, 1);
    dim3 grid(D_ / DC, H_ / 4, NVOL);   // 4 x 64 x 8 = 2048 blocks
    nms3d<<<grid, block, 0, stream>>>(x, out);
}

// Round 2
// 231.054 us; speedup vs baseline: 1.0345x; 1.0345x over previous
//
#include <hip/hip_runtime.h>

// NMS3D: x (4,2,64,256,256) f32, 3x3x3 neighborhood-max excluding center,
// edge padding == index clamping (exact match, incl. zeroed boundary shell).
//
// R2: z-prefetch (1-deep software pipeline) + reduced max-tree:
//   va = max(row_a, row_d) folds vertical halo rows BEFORE the horizontal
//   pass -> 4 shuffles/iter (was 6); cross8 = max(h3(va), nb(b));
//   vmax9 = max(cross8, b). DC=8 for finer load balance (4096 blocks).

constexpr int D_   = 64;
constexpr int H_   = 256;
constexpr int W_   = 256;
constexpr int HW_  = H_ * W_;
constexpr int NVOL = 8;    // B * CH
constexpr int DC   = 8;    // depth slices emitted per block

__device__ __forceinline__ float f3(float a, float b, float c) {
    return fmaxf(fmaxf(a, b), c);
}

__global__ __launch_bounds__(256, 4)
void nms3d(const float* __restrict__ x, float* __restrict__ out)
{
    const int tx = threadIdx.x;             // 0..63 -> covers W via float4
    const int ty = threadIdx.y;             // 0..3
    const int h  = (blockIdx.y << 2) + ty;  // 0..255
    const int n  = blockIdx.z;              // 0..7
    const int z0 = blockIdx.x * DC;

    const float* __restrict__ base  = x   + (size_t)n * D_ * HW_;
    float* __restrict__       obase = out + (size_t)n * D_ * HW_;

    const int r0 = (h == 0)      ? 0      : h - 1;
    const int r2 = (h == H_ - 1) ? H_ - 1 : h + 1;
    const int c  = tx << 2;

    // prefetch slice z0-1 (clamped)
    {
        const int zc = max(z0 - 1, 0);
        const float* sp = base + (size_t)zc * HW_;
        // fallthrough into loop-carried a,b,d below
    }
    const float* sp0 = base + (size_t)max(z0 - 1, 0) * HW_;
    float4 a = *(const float4*)(sp0 + r0 * W_ + c);
    float4 b = *(const float4*)(sp0 + h  * W_ + c);
    float4 d = *(const float4*)(sp0 + r2 * W_ + c);

    // rolling depth state
    float4 vm9_pp = make_float4(0.f, 0.f, 0.f, 0.f);  // vmax9[z-2]
    float4 vm9_p  = make_float4(0.f, 0.f, 0.f, 0.f);  // vmax9[z-1]
    float4 cr8_p  = make_float4(0.f, 0.f, 0.f, 0.f);  // cross8[z-1]
    float4 vprev  = make_float4(0.f, 0.f, 0.f, 0.f);  // v[z-1]

#pragma unroll
    for (int t = 0; t < DC + 2; ++t) {
        const int zi = z0 - 1 + t;

        // issue next slice's loads BEFORE computing current (overlap)
        const int zn = min(zi + 1, D_ - 1);
        const float* spn = base + (size_t)zn * HW_;
        const float4 an = *(const float4*)(spn + r0 * W_ + c);
        const float4 bn = *(const float4*)(spn + h  * W_ + c);
        const float4 dn = *(const float4*)(spn + r2 * W_ + c);

        // fold top/bottom rows first
        float4 va;
        va.x = fmaxf(a.x, d.x); va.y = fmaxf(a.y, d.y);
        va.z = fmaxf(a.z, d.z); va.w = fmaxf(a.w, d.w);

        // horizontal halo via wave shuffle (wave == one full W row)
        float vaL = __shfl_up(va.w, 1);  if (tx == 0)  vaL = va.x;
        float vaR = __shfl_down(va.x, 1);if (tx == 63) vaR = va.w;
        float bL  = __shfl_up(b.w, 1);   if (tx == 0)  bL  = b.x;
        float bR  = __shfl_down(b.x, 1); if (tx == 63) bR  = b.w;

        // horizontal 3-max of folded rows
        float4 hv;
        hv.x = f3(vaL, va.x, va.y);  hv.y = f3(va.x, va.y, va.z);
        hv.z = f3(va.y, va.z, va.w); hv.w = f3(va.z, va.w, vaR);
        // mid-row horizontal max EXCLUDING center
        float4 nb;
        nb.x = fmaxf(bL, b.y);  nb.y = fmaxf(b.x, b.z);
        nb.z = fmaxf(b.y, b.w); nb.w = fmaxf(b.z, bR);

        float4 c8, cur;                      // cross8[zi], vmax9[zi]
        c8.x  = fmaxf(hv.x, nb.x); c8.y  = fmaxf(hv.y, nb.y);
        c8.z  = fmaxf(hv.z, nb.z); c8.w  = fmaxf(hv.w, nb.w);
        cur.x = fmaxf(c8.x, b.x);  cur.y = fmaxf(c8.y, b.y);
        cur.z = fmaxf(c8.z, b.z);  cur.w = fmaxf(c8.w, b.w);

        if (zi > z0) {
            // emit out[zi-1]: max_nc = max(vmax9[zi-2], cross8[zi-1], vmax9[zi])
            float4 mx, o;
            mx.x = f3(vm9_pp.x, cr8_p.x, cur.x);
            mx.y = f3(vm9_pp.y, cr8_p.y, cur.y);
            mx.z = f3(vm9_pp.z, cr8_p.z, cur.z);
            mx.w = f3(vm9_pp.w, cr8_p.w, cur.w);
            o.x = vprev.x > mx.x ? vprev.x : 0.0f;
            o.y = vprev.y > mx.y ? vprev.y : 0.0f;
            o.z = vprev.z > mx.z ? vprev.z : 0.0f;
            o.w = vprev.w > mx.w ? vprev.w : 0.0f;
            *(float4*)(obase + (size_t)(zi - 1) * HW_ + (size_t)h * W_ + c) = o;
        }
        vm9_pp = vm9_p; vm9_p = cur; cr8_p = c8; vprev = b;
        a = an; b = bn; d = dn;
    }
}

extern "C" void kernel_launch(void* const* d_in, const int* in_sizes, int n_in,
                              void* d_out, int out_size, void* d_ws, size_t ws_size,
                              hipStream_t stream)
{
    const float* x = (const float*)d_in[0];
    float* out = (float*)d_out;
    dim3 block(64, 4, 1);
    dim3 grid(D_ / DC, H_ / 4, NVOL);   // 8 x 64 x 8 = 4096 blocks
    nms3d<<<grid, block, 0, stream>>>(x, out);
}